// Round 7
// baseline (253.563 us; speedup 1.0000x reference)
//
#include <hip/hip_runtime.h>
#include <math.h>

#define NB 32768
#define NK 10
#define NV 100000
#define ND 512
#define NSLOT 11                    // slot 0 = positive, 1..10 = negatives
#define NTASK (NB * NSLOT)          // 360448
#define BSHIFT 6
#define NBUCKET_PAD 2048            // (99999>>6)=1562 -> 1563 buckets, padded
#define NXCD 8

// ---- ws layout ----
// rec   : NTASK * 8  B  (uint2 {ctx_id, (b<<4)|slot})
// loss  : NTASK * 4  B
// hist  : NBUCKET_PAD * 4 B
// offs  : NBUCKET_PAD * 4 B   (scan result; consumed as cursors by scatter)
// part  : 2048 * 4 B          (E1 partials, 1408 used)
#define REC_OFF  0
#define LOSS_OFF (NTASK * 8)
#define HIST_OFF (LOSS_OFF + NTASK * 4)
#define OFFS_OFF (HIST_OFF + NBUCKET_PAD * 4)
#define PART_OFF (OFFS_OFF + NBUCKET_PAD * 4)
#define WS_NEED  (PART_OFF + 2048 * 4)

__global__ void zero_hist(unsigned* hist) {
    int i = blockIdx.x * blockDim.x + threadIdx.x;
    if (i < NBUCKET_PAD) hist[i] = 0;
}

__global__ __launch_bounds__(256) void hist_kernel(
    const int* __restrict__ context_ids, const int* __restrict__ neg_ids,
    unsigned* __restrict__ hist)
{
    int t = blockIdx.x * blockDim.x + threadIdx.x;
    if (t >= NTASK) return;
    int b = t / NSLOT, slot = t - b * NSLOT;
    int id = (slot == 0) ? context_ids[b] : neg_ids[b * NK + slot - 1];
    atomicAdd(&hist[id >> BSHIFT], 1u);
}

__global__ __launch_bounds__(1024) void scan_kernel(
    const unsigned* __restrict__ hist, unsigned* __restrict__ offs)
{
    __shared__ unsigned s[1024];
    const int t = threadIdx.x;
    const unsigned a = hist[2 * t], b = hist[2 * t + 1];
    s[t] = a + b;
    __syncthreads();
    for (int off = 1; off < 1024; off <<= 1) {
        unsigned v = (t >= off) ? s[t - off] : 0u;
        __syncthreads();
        s[t] += v;
        __syncthreads();
    }
    const unsigned excl = (t > 0) ? s[t - 1] : 0u;
    offs[2 * t]     = excl;
    offs[2 * t + 1] = excl + a;
}

__global__ __launch_bounds__(256) void scatter_kernel(
    const int* __restrict__ context_ids, const int* __restrict__ neg_ids,
    unsigned* __restrict__ offs, uint2* __restrict__ rec)
{
    int t = blockIdx.x * blockDim.x + threadIdx.x;
    if (t >= NTASK) return;
    int b = t / NSLOT, slot = t - b * NSLOT;
    int id = (slot == 0) ? context_ids[b] : neg_ids[b * NK + slot - 1];
    unsigned pos = atomicAdd(&offs[id >> BSHIFT], 1u);
    rec[pos] = make_uint2((unsigned)id, ((unsigned)b << 4) | (unsigned)slot);
}

// One 16-lane group per task, tasks in ctx-id-sorted order.
// ctx rows: consecutive tasks share rows -> L1/L2 hot, first touch streams.
// cv rows: random gather over ~57MB unique -> L3-resident.
__global__ __launch_bounds__(256) void dot_kernel(
    const uint2* __restrict__ rec,
    const int*   __restrict__ center_ids,
    const float* __restrict__ center_emb,
    const float* __restrict__ context_emb,
    float*       __restrict__ loss)
{
    // chunked XCD swizzle: each XCD gets a contiguous logical range
    const int nwg = NTASK / 16;                 // 22528, divisible by 8
    const int cpx = nwg / NXCD;                 // 2816
    const int lb  = (blockIdx.x % NXCD) * cpx + blockIdx.x / NXCD;

    const int tid = threadIdx.x;
    const int li  = tid & 15;
    const int g   = lb * 16 + (tid >> 4);       // task index

    const uint2 r  = rec[g];
    const int   id   = (int)r.x;
    const int   b    = (int)(r.y >> 4);
    const int   slot = (int)(r.y & 15u);

    const float4* cp  = (const float4*)(context_emb + (size_t)id * ND) + li;
    const float4* cvp = (const float4*)(center_emb + (size_t)center_ids[b] * ND) + li;

    __builtin_amdgcn_sched_barrier(0);
    float4 cx[8], cv[8];
#pragma unroll
    for (int j = 0; j < 8; ++j) cx[j] = cp[16 * j];
#pragma unroll
    for (int j = 0; j < 8; ++j) cv[j] = cvp[16 * j];
    __builtin_amdgcn_sched_barrier(0);

    float p = 0.0f;
#pragma unroll
    for (int j = 0; j < 8; ++j)
        p += cv[j].x * cx[j].x + cv[j].y * cx[j].y
           + cv[j].z * cx[j].z + cv[j].w * cx[j].w;
#pragma unroll
    for (int off = 1; off < 16; off <<= 1) p += __shfl_xor(p, off, 64);

    if (li == 0) {
        float t = fminf(fmaxf(p, -10.0f), 10.0f);
        t = (slot == 0) ? -t : t;
        loss[b * NSLOT + slot] = __logf(1.0f + __expf(t));  // softplus
    }
}

// deterministic fixed-order reduction: 1408 blocks x 256 = NTASK exactly
__global__ __launch_bounds__(256) void reduce1(
    const float* __restrict__ loss, float* __restrict__ part)
{
    __shared__ float ls[256];
    ls[threadIdx.x] = loss[blockIdx.x * 256 + threadIdx.x];
    __syncthreads();
    for (int w = 128; w > 0; w >>= 1) {
        if (threadIdx.x < w) ls[threadIdx.x] += ls[threadIdx.x + w];
        __syncthreads();
    }
    if (threadIdx.x == 0) part[blockIdx.x] = ls[0];
}

__global__ __launch_bounds__(1024) void reduce2(
    const float* __restrict__ part, float* __restrict__ out, int n, float scale)
{
    __shared__ float ls[1024];
    float s = 0.0f;
    for (int i = threadIdx.x; i < n; i += 1024) s += part[i];
    ls[threadIdx.x] = s;
    __syncthreads();
    for (int w = 512; w > 0; w >>= 1) {
        if (threadIdx.x < w) ls[threadIdx.x] += ls[threadIdx.x + w];
        __syncthreads();
    }
    if (threadIdx.x == 0) out[0] = ls[0] * scale;
}

// ---------------- fallback (proven R6 path) for small ws ----------------
#define WPB 4
#define FGRID (NB / WPB)
__global__ __launch_bounds__(256) void sgns_fallback(
    const int* __restrict__ center_ids, const int* __restrict__ context_ids,
    const int* __restrict__ neg_ids, const float* __restrict__ center_emb,
    const float* __restrict__ context_emb, float* __restrict__ partials)
{
    const int tid = threadIdx.x, lane = tid & 63, wave = tid >> 6;
    const int grp = lane >> 4, li = lane & 15;
    const int b = blockIdx.x * WPB + wave;
    const int ctx_id = context_ids[b];
    int rid[3];
#pragma unroll
    for (int r = 0; r < 3; ++r) {
        const int s = r * 4 + grp;
        rid[r] = (s == 0 || s == 11) ? ctx_id : neg_ids[b * NK + (s - 1)];
    }
    const float4* cvp = (const float4*)(center_emb  + (size_t)center_ids[b] * ND) + li;
    const float4* rpA = (const float4*)(context_emb + (size_t)rid[0] * ND) + li;
    const float4* rpB = (const float4*)(context_emb + (size_t)rid[1] * ND) + li;
    const float4* rpC = (const float4*)(context_emb + (size_t)rid[2] * ND) + li;
    float4 cv[8], ra[8], rb[8], rc[8];
#pragma unroll
    for (int j = 0; j < 8; ++j) cv[j] = cvp[16 * j];
#pragma unroll
    for (int j = 0; j < 8; ++j) ra[j] = rpA[16 * j];
#pragma unroll
    for (int j = 0; j < 8; ++j) rb[j] = rpB[16 * j];
#pragma unroll
    for (int j = 0; j < 8; ++j) rc[j] = rpC[16 * j];
    float lacc = 0.0f;
    {
        float p = 0.0f;
#pragma unroll
        for (int j = 0; j < 8; ++j)
            p += cv[j].x*ra[j].x + cv[j].y*ra[j].y + cv[j].z*ra[j].z + cv[j].w*ra[j].w;
#pragma unroll
        for (int off = 1; off < 16; off <<= 1) p += __shfl_xor(p, off, 64);
        float t = fminf(fmaxf(p, -10.0f), 10.0f);
        t = (grp == 0) ? -t : t;
        lacc += __logf(1.0f + __expf(t));
    }
    {
        float p = 0.0f;
#pragma unroll
        for (int j = 0; j < 8; ++j)
            p += cv[j].x*rb[j].x + cv[j].y*rb[j].y + cv[j].z*rb[j].z + cv[j].w*rb[j].w;
#pragma unroll
        for (int off = 1; off < 16; off <<= 1) p += __shfl_xor(p, off, 64);
        float t = fminf(fmaxf(p, -10.0f), 10.0f);
        lacc += __logf(1.0f + __expf(t));
    }
    {
        float p = 0.0f;
#pragma unroll
        for (int j = 0; j < 8; ++j)
            p += cv[j].x*rc[j].x + cv[j].y*rc[j].y + cv[j].z*rc[j].z + cv[j].w*rc[j].w;
#pragma unroll
        for (int off = 1; off < 16; off <<= 1) p += __shfl_xor(p, off, 64);
        float t = fminf(fmaxf(p, -10.0f), 10.0f);
        float l = __logf(1.0f + __expf(t));
        lacc += (grp == 3) ? 0.0f : l;
    }
    lacc += __shfl_xor(lacc, 16, 64);
    lacc += __shfl_xor(lacc, 32, 64);
    __shared__ float ls[WPB];
    if (lane == 0) ls[wave] = lacc;
    __syncthreads();
    if (tid == 0) partials[blockIdx.x] = ls[0] + ls[1] + ls[2] + ls[3];
}

extern "C" void kernel_launch(void* const* d_in, const int* in_sizes, int n_in,
                              void* d_out, int out_size, void* d_ws, size_t ws_size,
                              hipStream_t stream) {
    const int*   center_ids  = (const int*)d_in[0];
    const int*   context_ids = (const int*)d_in[1];
    const int*   neg_ids     = (const int*)d_in[2];
    const float* center_emb  = (const float*)d_in[3];
    const float* context_emb = (const float*)d_in[4];
    float* out = (float*)d_out;
    char*  ws  = (char*)d_ws;

    if (ws_size >= (size_t)WS_NEED) {
        uint2*    rec  = (uint2*)(ws + REC_OFF);
        float*    loss = (float*)(ws + LOSS_OFF);
        unsigned* hist = (unsigned*)(ws + HIST_OFF);
        unsigned* offs = (unsigned*)(ws + OFFS_OFF);
        float*    part = (float*)(ws + PART_OFF);

        zero_hist<<<NBUCKET_PAD / 256, 256, 0, stream>>>(hist);
        hist_kernel<<<(NTASK + 255) / 256, 256, 0, stream>>>(context_ids, neg_ids, hist);
        scan_kernel<<<1, 1024, 0, stream>>>(hist, offs);
        scatter_kernel<<<(NTASK + 255) / 256, 256, 0, stream>>>(context_ids, neg_ids, offs, rec);
        dot_kernel<<<NTASK / 16, 256, 0, stream>>>(rec, center_ids, center_emb, context_emb, loss);
        reduce1<<<NTASK / 256, 256, 0, stream>>>(loss, part);
        reduce2<<<1, 1024, 0, stream>>>(part, out, NTASK / 256, 1.0f / (float)NB);
    } else {
        float* partials = (float*)d_ws;
        sgns_fallback<<<FGRID, 256, 0, stream>>>(center_ids, context_ids, neg_ids,
                                                 center_emb, context_emb, partials);
        reduce2<<<1, 1024, 0, stream>>>(partials, out, FGRID, 1.0f / (float)NB);
    }
}

// Round 9
// 114.957 us; speedup vs baseline: 2.2057x; 2.2057x over previous
//
#include <hip/hip_runtime.h>
#include <math.h>

#define NB 32768
#define NK 10
#define ND 512
#define WPB 4               // waves per block
#define GRID (NB / WPB)

typedef float vfloat4 __attribute__((ext_vector_type(4)));

// One wave per batch element; wave = 4 groups of 16 lanes.
// Each group computes one full 512-float dot per round (3 rounds cover
// ctx + 10 negs + 1 dummy). Lane li of a group owns float4s {li + 16j}.
// All 32 row-loads issued in ONE fenced cluster (monotone vmcnt drain).
// Center-row loads are NON-TEMPORAL: center gather is 64MB demand / 57MB
// unique (1.1x reuse) and only pollutes L3; ctx rows (3.7x reuse, 195MB
// unique) get the retention budget instead.
__global__ __launch_bounds__(256) void sgns_main(
    const int*   __restrict__ center_ids,
    const int*   __restrict__ context_ids,
    const int*   __restrict__ neg_ids,
    const float* __restrict__ center_emb,
    const float* __restrict__ context_emb,
    float*       __restrict__ partials)
{
    const int tid  = threadIdx.x;
    const int lane = tid & 63;
    const int wave = tid >> 6;
    const int grp  = lane >> 4;     // 0..3
    const int li   = lane & 15;     // lane within group
    const int b    = blockIdx.x * WPB + wave;

    const int ctx_id = context_ids[b];
    // slot s = r*4 + grp: s=0 -> positive ctx dot, s=1..10 -> neg s-1,
    // s=11 -> dummy (re-dot ctx row, loss zeroed; row is cache-hot)
    int rid[3];
#pragma unroll
    for (int r = 0; r < 3; ++r) {
        const int s = r * 4 + grp;
        rid[r] = (s == 0 || s == 11) ? ctx_id : neg_ids[b * NK + (s - 1)];
    }

    const vfloat4* cvp = (const vfloat4*)(center_emb  + (size_t)center_ids[b] * ND) + li;
    const float4*  rpA = (const float4*)(context_emb + (size_t)rid[0] * ND) + li;
    const float4*  rpB = (const float4*)(context_emb + (size_t)rid[1] * ND) + li;
    const float4*  rpC = (const float4*)(context_emb + (size_t)rid[2] * ND) + li;

    __builtin_amdgcn_sched_barrier(0);

    // ---- single issue cluster: 32 independent dwordx4 loads in flight ----
    vfloat4 cv[8];
    float4  ra[8], rb[8], rc[8];
#pragma unroll
    for (int j = 0; j < 8; ++j) cv[j] = __builtin_nontemporal_load(&cvp[16 * j]);
#pragma unroll
    for (int j = 0; j < 8; ++j) ra[j] = rpA[16 * j];
#pragma unroll
    for (int j = 0; j < 8; ++j) rb[j] = rpB[16 * j];
#pragma unroll
    for (int j = 0; j < 8; ++j) rc[j] = rpC[16 * j];

    __builtin_amdgcn_sched_barrier(0);

    float lacc = 0.0f;

    // ---- round 0 ----
    {
        float p = 0.0f;
#pragma unroll
        for (int j = 0; j < 8; ++j)
            p += cv[j].x * ra[j].x + cv[j].y * ra[j].y
               + cv[j].z * ra[j].z + cv[j].w * ra[j].w;
#pragma unroll
        for (int off = 1; off < 16; off <<= 1) p += __shfl_xor(p, off, 64);
        float t = fminf(fmaxf(p, -10.0f), 10.0f);
        t = (grp == 0) ? -t : t;                 // slot 0 is the positive
        lacc += __logf(1.0f + __expf(t));        // softplus(t)
    }

    // ---- round 1 ----
    {
        float p = 0.0f;
#pragma unroll
        for (int j = 0; j < 8; ++j)
            p += cv[j].x * rb[j].x + cv[j].y * rb[j].y
               + cv[j].z * rb[j].z + cv[j].w * rb[j].w;
#pragma unroll
        for (int off = 1; off < 16; off <<= 1) p += __shfl_xor(p, off, 64);
        float t = fminf(fmaxf(p, -10.0f), 10.0f);
        lacc += __logf(1.0f + __expf(t));        // slots 4..7, all negatives
    }

    // ---- round 2 ----
    {
        float p = 0.0f;
#pragma unroll
        for (int j = 0; j < 8; ++j)
            p += cv[j].x * rc[j].x + cv[j].y * rc[j].y
               + cv[j].z * rc[j].z + cv[j].w * rc[j].w;
#pragma unroll
        for (int off = 1; off < 16; off <<= 1) p += __shfl_xor(p, off, 64);
        float t = fminf(fmaxf(p, -10.0f), 10.0f);
        float l = __logf(1.0f + __expf(t));
        lacc += (grp == 3) ? 0.0f : l;           // slot 11 is the dummy
    }

    // sum the 4 group losses across the wave
    lacc += __shfl_xor(lacc, 16, 64);
    lacc += __shfl_xor(lacc, 32, 64);

    __shared__ float ls[WPB];
    if (lane == 0) ls[wave] = lacc;
    __syncthreads();
    if (tid == 0)
        partials[blockIdx.x] = ls[0] + ls[1] + ls[2] + ls[3];
}

// Deterministic final reduction of the 8192 per-block partials -> mean.
__global__ __launch_bounds__(1024) void sgns_finish(
    const float* __restrict__ partials, float* __restrict__ out, int n)
{
    __shared__ float ls[1024];
    float s = 0.0f;
    for (int i = threadIdx.x; i < n; i += 1024) s += partials[i];
    ls[threadIdx.x] = s;
    __syncthreads();
    for (int w = 512; w > 0; w >>= 1) {
        if (threadIdx.x < w) ls[threadIdx.x] += ls[threadIdx.x + w];
        __syncthreads();
    }
    if (threadIdx.x == 0) out[0] = ls[0] * (1.0f / (float)NB);
}

extern "C" void kernel_launch(void* const* d_in, const int* in_sizes, int n_in,
                              void* d_out, int out_size, void* d_ws, size_t ws_size,
                              hipStream_t stream) {
    const int*   center_ids  = (const int*)d_in[0];
    const int*   context_ids = (const int*)d_in[1];
    const int*   neg_ids     = (const int*)d_in[2];
    const float* center_emb  = (const float*)d_in[3];
    const float* context_emb = (const float*)d_in[4];
    float* out      = (float*)d_out;
    float* partials = (float*)d_ws;   // GRID floats = 32 KB << ws_size

    sgns_main<<<GRID, 256, 0, stream>>>(center_ids, context_ids, neg_ids,
                                        center_emb, context_emb, partials);
    sgns_finish<<<1, 1024, 0, stream>>>(partials, out, GRID);
}